// Round 11
// baseline (3044.476 us; speedup 1.0000x reference)
//
#include <hip/hip_runtime.h>
#include <hip/hip_bf16.h>

// MoE FFN, top-1 switch routing. fp32 end-to-end (no fp32 MFMA on CDNA4).
// Sparse dispatch via device-built work-list of alive (expert,row-block).
//
// R9: single-buffered LDS (R8 dbuf reverted: cost VGPR 140->184 + 2x LDS
// -> lost a resident block, gained nothing). Micro-tile 16x8 (block tile
// 256x128): 128 FMA / 6 ds_read_b128 raises the LDS-throughput ceiling
// from 67% -> 89% VALU (R7/R8 both pinned at VALUBusy ~45%, LDS-bound).
// XCD-chunk swizzle kept (FETCH 549->336MB proven in R8).
//
// GEMM2 split-K=4; s=0 partial -> d_out, s>0 -> ws; reduce applies
// sum + bias + route_p.

#define D_MODEL 1024
#define MLP_DIM 4096
#define N_EXPERTS 8
#define N_TOK 4096
#define KSPLIT 4
#define ROWTILE 256
#define WLMAX 24   // Sum ceil(cnt_e/256) <= 23 for any routing (+1 pad)
#define NWG 768    // 32*WLMAX (GEMM1) = 8*4*WLMAX (GEMM2)
#define CHUNK (NWG / 8)

// ---------------- router: logits -> softmax max prob + argmax ----------------
__global__ __launch_bounds__(64) void router_kernel(
    const float* __restrict__ x, const float* __restrict__ w_gate,
    const float* __restrict__ b_gate, int* __restrict__ route_idx,
    float* __restrict__ route_p) {
  int t = blockIdx.x;
  int lane = threadIdx.x;
  const float* xr = x + (size_t)t * D_MODEL;
  float acc[N_EXPERTS];
#pragma unroll
  for (int e = 0; e < N_EXPERTS; ++e) acc[e] = 0.f;
#pragma unroll
  for (int i = 0; i < D_MODEL / 64; ++i) {
    int idx = i * 64 + lane;
    float xv = xr[idx];
    const float* wg = w_gate + (size_t)idx * N_EXPERTS;
#pragma unroll
    for (int e = 0; e < N_EXPERTS; ++e) acc[e] += xv * wg[e];
  }
#pragma unroll
  for (int off = 32; off >= 1; off >>= 1) {
#pragma unroll
    for (int e = 0; e < N_EXPERTS; ++e) acc[e] += __shfl_xor(acc[e], off, 64);
  }
  if (lane == 0) {
    float l[N_EXPERTS];
#pragma unroll
    for (int e = 0; e < N_EXPERTS; ++e) l[e] = acc[e] + b_gate[e];
    // strict > : first-max tiebreak, matches jnp.argmax (softmax monotonic)
    float m = l[0];
    int bi = 0;
#pragma unroll
    for (int e = 1; e < N_EXPERTS; ++e) {
      if (l[e] > m) { m = l[e]; bi = e; }
    }
    float s = 0.f;
#pragma unroll
    for (int e = 0; e < N_EXPERTS; ++e) s += expf(l[e] - m);
    route_idx[t] = bi;
    route_p[t] = 1.0f / s;  // max softmax prob = exp(0)/sum
  }
}

// ---------------- bucketize tokens per expert ----------------
__global__ void bucket_kernel(const int* __restrict__ route_idx,
                              int* __restrict__ counts,
                              int* __restrict__ bucket) {
  int t = blockIdx.x * blockDim.x + threadIdx.x;
  if (t < N_TOK) {
    int e = route_idx[t];
    int pos = atomicAdd(&counts[e], 1);
    bucket[e * N_TOK + pos] = t;
  }
}

// ---------------- work-list: alive (expert,row0) pairs ----------------
__global__ void worklist_kernel(const int* __restrict__ counts,
                                int* __restrict__ mlist_e,
                                int* __restrict__ mlist_r,
                                int* __restrict__ Mp) {
  if (threadIdx.x == 0) {
    int m = 0;
    for (int e = 0; e < N_EXPERTS; ++e) {
      int c = counts[e];
      for (int r = 0; r < c; r += ROWTILE) {
        mlist_e[m] = e;
        mlist_r[m] = r;
        ++m;
      }
    }
    *Mp = m;  // <= 23
  }
}

// ---------------- gathered expert GEMM (work-list driven) ----------------
// 256x128 tile, BK=16, 256 threads, 16x8 micro-tile (4 row-quads at
// hm*64+ty*4, col-quads at tx*4 and tx*4+64). Per kk: 128 FMA / 6
// ds_read_b128 -> LDS ceiling 89% VALU. Single-buffer, 2 barriers/iter;
// next k-tile register-prefetched during compute (proven R7 schedule).
// Work decode from XCD-chunk-swizzled id (w = (L%8)*CHUNK + L/8):
//   GEMM1: m = w%WLMAX, col = w/WLMAX (0..31)
//   GEMM2: m = w%WLMAX, cs = w/WLMAX, col = cs&7, s = cs>>3
template <bool SPLIT>
__global__ __launch_bounds__(256, 2) void expert_gemm(
    const float* __restrict__ A, const float* __restrict__ B,
    const float* __restrict__ bias, float* __restrict__ C0,
    float* __restrict__ partials, const int* __restrict__ bucket,
    const int* __restrict__ counts, const int* __restrict__ mlist_e,
    const int* __restrict__ mlist_r, const int* __restrict__ Mp,
    int Kstride, int Ncols) {
  constexpr int BM = 256, BN = 128, BK = 16;
  constexpr int LDA = BM + 4, LDB = BN + 4;  // break pow2 strides
  const int L = blockIdx.x;
  const int w = (L & 7) * CHUNK + (L >> 3);  // bijective XCD chunking
  int m, colblk, kbeg, kend;
  float* Cp;
  if (SPLIT) {
    m = w % WLMAX;
    int cs = w / WLMAX;       // 0..31
    colblk = cs & 7;
    int s = cs >> 3;          // 0..3
    kbeg = s * (MLP_DIM / KSPLIT);
    kend = kbeg + (MLP_DIM / KSPLIT);
    Cp = (s == 0) ? C0 : partials + (size_t)(s - 1) * N_TOK * D_MODEL;
  } else {
    m = w % WLMAX;
    colblk = w / WLMAX;       // 0..31
    kbeg = 0;
    kend = Kstride;
    Cp = C0;
  }
  if (m >= *Mp) return;
  const int e = mlist_e[m];
  const int row0 = mlist_r[m];
  const int cnt = counts[e];
  const int col0 = colblk * BN;

  __shared__ float As[BK][LDA];  // k-major (transposed store), 16x260
  __shared__ float Bs[BK][LDB];
  __shared__ int tokS[BM];

  const int tid = threadIdx.x;
  {
    int r = row0 + tid;
    tokS[tid] = (r < cnt) ? bucket[e * N_TOK + r] : -1;
  }
  __syncthreads();

  // A-load map: rows {ar+64j, j=0..3}, k-chunk ak (4 floats) = 4 float4/thr
  const int ar = tid >> 2;
  const int ak = (tid & 3) * 4;
  // B-load map: k-row bk, col-chunk bj (8 floats = 2 float4)
  const int bk = tid >> 4;
  const int bj = (tid & 15) * 8;

  const int tx = tid & 15;  // cols tx*4 and tx*4+64
  const int ty = tid >> 4;  // row-quad base ty*4 (+64*hm)

  float acc[4][2][4][4];
#pragma unroll
  for (int hm = 0; hm < 4; ++hm)
#pragma unroll
    for (int hn = 0; hn < 2; ++hn)
#pragma unroll
      for (int i = 0; i < 4; ++i)
#pragma unroll
        for (int j = 0; j < 4; ++j) acc[hm][hn][i][j] = 0.f;

  const float* __restrict__ Ap[4];
#pragma unroll
  for (int j = 0; j < 4; ++j) {
    int tk = tokS[ar + 64 * j];
    Ap[j] = (tk >= 0) ? A + (size_t)tk * Kstride + ak : nullptr;
  }
  const float* __restrict__ Bp =
      B + (size_t)e * Kstride * Ncols + (size_t)bk * Ncols + col0 + bj;

  float4 a[4], b0, b1;

#define LOADTILE(K0)                                          \
  _Pragma("unroll") for (int j = 0; j < 4; ++j) {             \
    a[j] = make_float4(0.f, 0.f, 0.f, 0.f);                   \
    if (Ap[j]) a[j] = *(const float4*)(Ap[j] + (K0));         \
  }                                                           \
  {                                                           \
    const float* bp = Bp + (size_t)(K0) * Ncols;              \
    b0 = *(const float4*)bp;                                  \
    b1 = *(const float4*)(bp + 4);                            \
  }

  // prologue: stage tile 0 into regs
  LOADTILE(kbeg);

  const int nt = (kend - kbeg) / BK;
  for (int t = 0; t < nt; ++t) {
    __syncthreads();  // previous compute done before overwrite
#pragma unroll
    for (int j = 0; j < 4; ++j) {
      As[ak + 0][ar + 64 * j] = a[j].x;
      As[ak + 1][ar + 64 * j] = a[j].y;
      As[ak + 2][ar + 64 * j] = a[j].z;
      As[ak + 3][ar + 64 * j] = a[j].w;
    }
    *(float4*)&Bs[bk][bj] = b0;
    *(float4*)&Bs[bk][bj + 4] = b1;
    __syncthreads();

    if (t + 1 < nt) {  // prefetch next tile into regs (overlaps compute)
      const int kn = kbeg + (t + 1) * BK;
      LOADTILE(kn);
    }

#pragma unroll
    for (int kk = 0; kk < BK; ++kk) {
      float av[4][4], bv[2][4];
#pragma unroll
      for (int hm = 0; hm < 4; ++hm)
        *(float4*)&av[hm][0] = *(const float4*)&As[kk][ty * 4 + 64 * hm];
      *(float4*)&bv[0][0] = *(const float4*)&Bs[kk][tx * 4];
      *(float4*)&bv[1][0] = *(const float4*)&Bs[kk][tx * 4 + 64];
#pragma unroll
      for (int hm = 0; hm < 4; ++hm)
#pragma unroll
        for (int hn = 0; hn < 2; ++hn)
#pragma unroll
          for (int i = 0; i < 4; ++i)
#pragma unroll
            for (int j = 0; j < 4; ++j)
              acc[hm][hn][i][j] += av[hm][i] * bv[hn][j];
    }
  }
#undef LOADTILE

  if (SPLIT) {
    // raw k-slice partial, no bias/epilogue
#pragma unroll
    for (int hm = 0; hm < 4; ++hm) {
#pragma unroll
      for (int i = 0; i < 4; ++i) {
        int r = hm * 64 + ty * 4 + i;
        if (row0 + r < cnt) {
          int tok = tokS[r];
#pragma unroll
          for (int hn = 0; hn < 2; ++hn) {
            float4 o;
            o.x = acc[hm][hn][i][0];
            o.y = acc[hm][hn][i][1];
            o.z = acc[hm][hn][i][2];
            o.w = acc[hm][hn][i][3];
            *(float4*)(Cp + (size_t)tok * Ncols + col0 + hn * 64 + tx * 4) = o;
          }
        }
      }
    }
  } else {
    float4 bvv[2];
    bvv[0] = *(const float4*)(bias + (size_t)e * Ncols + col0 + tx * 4);
    bvv[1] = *(const float4*)(bias + (size_t)e * Ncols + col0 + tx * 4 + 64);
#pragma unroll
    for (int hm = 0; hm < 4; ++hm) {
#pragma unroll
      for (int i = 0; i < 4; ++i) {
        int r = hm * 64 + ty * 4 + i;
        if (row0 + r < cnt) {
          int tok = tokS[r];
#pragma unroll
          for (int hn = 0; hn < 2; ++hn) {
            const float* bb = (const float*)&bvv[hn];
            float4 o;
            o.x = fmaxf(acc[hm][hn][i][0] + bb[0], 0.f);
            o.y = fmaxf(acc[hm][hn][i][1] + bb[1], 0.f);
            o.z = fmaxf(acc[hm][hn][i][2] + bb[2], 0.f);
            o.w = fmaxf(acc[hm][hn][i][3] + bb[3], 0.f);
            *(float4*)(Cp + (size_t)tok * Ncols + col0 + hn * 64 + tx * 4) = o;
          }
        }
      }
    }
  }
}

// ---------------- split-K reduce + bias + route_p epilogue ----------------
// one block per token, 256 threads = 256 float4 covering D_MODEL=1024 cols.
__global__ __launch_bounds__(256) void moe_reduce_kernel(
    float* __restrict__ out, const float* __restrict__ partials,
    const float* __restrict__ b2, const int* __restrict__ route_idx,
    const float* __restrict__ route_p) {
  int tok = blockIdx.x;
  int c = threadIdx.x * 4;
  int e = route_idx[tok];
  float p = route_p[tok];
  size_t off = (size_t)tok * D_MODEL + c;
  float4 s = *(const float4*)(out + off);
  const size_t stride = (size_t)N_TOK * D_MODEL;
#pragma unroll
  for (int sp = 0; sp < KSPLIT - 1; ++sp) {
    float4 v = *(const float4*)(partials + sp * stride + off);
    s.x += v.x; s.y += v.y; s.z += v.z; s.w += v.w;
  }
  float4 bv = *(const float4*)(b2 + (size_t)e * D_MODEL + c);
  s.x = (s.x + bv.x) * p;
  s.y = (s.y + bv.y) * p;
  s.z = (s.z + bv.z) * p;
  s.w = (s.w + bv.w) * p;
  *(float4*)(out + off) = s;
}

extern "C" void kernel_launch(void* const* d_in, const int* in_sizes, int n_in,
                              void* d_out, int out_size, void* d_ws,
                              size_t ws_size, hipStream_t stream) {
  const float* x = (const float*)d_in[0];
  const float* w_gate = (const float*)d_in[1];
  const float* b_gate = (const float*)d_in[2];
  const float* W1 = (const float*)d_in[3];
  const float* b1 = (const float*)d_in[4];
  const float* W2 = (const float*)d_in[5];
  const float* b2 = (const float*)d_in[6];
  float* out = (float*)d_out;

  // workspace layout (~112.2 MiB)
  char* ws = (char*)d_ws;
  int* route_idx = (int*)ws;                         // 16 KiB
  float* route_p = (float*)(ws + 16384);             // 16 KiB
  int* counts = (int*)(ws + 32768);                  // 32 B
  int* Mp = (int*)(ws + 32896);                      // 4 B
  int* mlist_e = (int*)(ws + 33024);                 // <=96 B
  int* mlist_r = (int*)(ws + 33280);                 // <=96 B
  int* bucket = (int*)(ws + 33536);                  // 128 KiB
  float* H = (float*)(ws + 165888);                  // 64 MiB
  float* partials = (float*)(ws + 165888 + (size_t)67108864);  // 48 MiB

  hipMemsetAsync(counts, 0, N_EXPERTS * sizeof(int), stream);
  router_kernel<<<N_TOK, 64, 0, stream>>>(x, w_gate, b_gate, route_idx, route_p);
  bucket_kernel<<<N_TOK / 256, 256, 0, stream>>>(route_idx, counts, bucket);
  worklist_kernel<<<1, 64, 0, stream>>>(counts, mlist_e, mlist_r, Mp);
  // layer 1: H = relu(Xg @ W1 + b1); 768 compact blocks
  expert_gemm<false><<<NWG, 256, 0, stream>>>(x, W1, b1, H, nullptr, bucket,
                                              counts, mlist_e, mlist_r, Mp,
                                              D_MODEL, MLP_DIM);
  // layer 2 pass A: split-K=4 raw partials (s=0 -> out, s>0 -> ws)
  expert_gemm<true><<<NWG, 256, 0, stream>>>(H, W2, nullptr, out, partials,
                                             bucket, counts, mlist_e, mlist_r,
                                             Mp, MLP_DIM, D_MODEL);
  // layer 2 pass B: sum partials + bias + route_p scale
  moe_reduce_kernel<<<N_TOK, 256, 0, stream>>>(out, partials, b2, route_idx,
                                               route_p);
}

// Round 12
// 1711.377 us; speedup vs baseline: 1.7790x; 1.7790x over previous
//
#include <hip/hip_runtime.h>
#include <hip/hip_bf16.h>

// MoE FFN, top-1 switch routing. fp32 end-to-end (no fp32 MFMA on CDNA4).
// Sparse dispatch via device-built work-list of alive (expert,row-block).
//
// R12: __launch_bounds__(256) single-arg. R11's (256,2) capped the
// allocator at 128 VGPR -> the 16x8 micro-tile's 128-reg accumulator
// SPILLED to scratch (measured: VGPR=128, WRITE_SIZE 2.15GB/dispatch =
// 33x output, 1650us). Single-arg allowed 140/184 VGPR in R7/R8.
// Micro-tile 16x8 (block tile 256x128): 128 FMA / 6 ds_read_b128 ->
// LDS-throughput ceiling 89% VALU (R7 8x8 ceiling was 67%, measured 45%).
// Work-list + XCD-chunk swizzle kept (FETCH 549->336MB proven R8).
//
// GEMM2 split-K=4; s=0 partial -> d_out, s>0 -> ws; reduce applies
// sum + bias + route_p.

#define D_MODEL 1024
#define MLP_DIM 4096
#define N_EXPERTS 8
#define N_TOK 4096
#define KSPLIT 4
#define ROWTILE 256
#define WLMAX 24   // Sum ceil(cnt_e/256) <= 23 for any routing (+1 pad)
#define NWG 768    // 32*WLMAX (GEMM1) = 8*4*WLMAX (GEMM2)
#define CHUNK (NWG / 8)

// ---------------- router: logits -> softmax max prob + argmax ----------------
__global__ __launch_bounds__(64) void router_kernel(
    const float* __restrict__ x, const float* __restrict__ w_gate,
    const float* __restrict__ b_gate, int* __restrict__ route_idx,
    float* __restrict__ route_p) {
  int t = blockIdx.x;
  int lane = threadIdx.x;
  const float* xr = x + (size_t)t * D_MODEL;
  float acc[N_EXPERTS];
#pragma unroll
  for (int e = 0; e < N_EXPERTS; ++e) acc[e] = 0.f;
#pragma unroll
  for (int i = 0; i < D_MODEL / 64; ++i) {
    int idx = i * 64 + lane;
    float xv = xr[idx];
    const float* wg = w_gate + (size_t)idx * N_EXPERTS;
#pragma unroll
    for (int e = 0; e < N_EXPERTS; ++e) acc[e] += xv * wg[e];
  }
#pragma unroll
  for (int off = 32; off >= 1; off >>= 1) {
#pragma unroll
    for (int e = 0; e < N_EXPERTS; ++e) acc[e] += __shfl_xor(acc[e], off, 64);
  }
  if (lane == 0) {
    float l[N_EXPERTS];
#pragma unroll
    for (int e = 0; e < N_EXPERTS; ++e) l[e] = acc[e] + b_gate[e];
    // strict > : first-max tiebreak, matches jnp.argmax (softmax monotonic)
    float m = l[0];
    int bi = 0;
#pragma unroll
    for (int e = 1; e < N_EXPERTS; ++e) {
      if (l[e] > m) { m = l[e]; bi = e; }
    }
    float s = 0.f;
#pragma unroll
    for (int e = 0; e < N_EXPERTS; ++e) s += expf(l[e] - m);
    route_idx[t] = bi;
    route_p[t] = 1.0f / s;  // max softmax prob = exp(0)/sum
  }
}

// ---------------- bucketize tokens per expert ----------------
__global__ void bucket_kernel(const int* __restrict__ route_idx,
                              int* __restrict__ counts,
                              int* __restrict__ bucket) {
  int t = blockIdx.x * blockDim.x + threadIdx.x;
  if (t < N_TOK) {
    int e = route_idx[t];
    int pos = atomicAdd(&counts[e], 1);
    bucket[e * N_TOK + pos] = t;
  }
}

// ---------------- work-list: alive (expert,row0) pairs ----------------
__global__ void worklist_kernel(const int* __restrict__ counts,
                                int* __restrict__ mlist_e,
                                int* __restrict__ mlist_r,
                                int* __restrict__ Mp) {
  if (threadIdx.x == 0) {
    int m = 0;
    for (int e = 0; e < N_EXPERTS; ++e) {
      int c = counts[e];
      for (int r = 0; r < c; r += ROWTILE) {
        mlist_e[m] = e;
        mlist_r[m] = r;
        ++m;
      }
    }
    *Mp = m;  // <= 23
  }
}

// ---------------- gathered expert GEMM (work-list driven) ----------------
// 256x128 tile, BK=16, 256 threads, 16x8 micro-tile (4 row-quads at
// hm*64+ty*4, col-quads at tx*4 and tx*4+64). Per kk: 128 FMA / 6
// ds_read_b128 -> LDS ceiling 89% VALU. Single-buffer, 2 barriers/iter;
// next k-tile register-prefetched during compute (proven R7 schedule).
// Work decode from XCD-chunk-swizzled id (w = (L%8)*CHUNK + L/8):
//   GEMM1: m = w%WLMAX, col = w/WLMAX (0..31)
//   GEMM2: m = w%WLMAX, cs = w/WLMAX, col = cs&7, s = cs>>3
template <bool SPLIT>
__global__ __launch_bounds__(256) void expert_gemm(
    const float* __restrict__ A, const float* __restrict__ B,
    const float* __restrict__ bias, float* __restrict__ C0,
    float* __restrict__ partials, const int* __restrict__ bucket,
    const int* __restrict__ counts, const int* __restrict__ mlist_e,
    const int* __restrict__ mlist_r, const int* __restrict__ Mp,
    int Kstride, int Ncols) {
  constexpr int BM = 256, BN = 128, BK = 16;
  constexpr int LDA = BM + 4, LDB = BN + 4;  // break pow2 strides
  const int L = blockIdx.x;
  const int w = (L & 7) * CHUNK + (L >> 3);  // bijective XCD chunking
  int m, colblk, kbeg, kend;
  float* Cp;
  if (SPLIT) {
    m = w % WLMAX;
    int cs = w / WLMAX;       // 0..31
    colblk = cs & 7;
    int s = cs >> 3;          // 0..3
    kbeg = s * (MLP_DIM / KSPLIT);
    kend = kbeg + (MLP_DIM / KSPLIT);
    Cp = (s == 0) ? C0 : partials + (size_t)(s - 1) * N_TOK * D_MODEL;
  } else {
    m = w % WLMAX;
    colblk = w / WLMAX;       // 0..31
    kbeg = 0;
    kend = Kstride;
    Cp = C0;
  }
  if (m >= *Mp) return;
  const int e = mlist_e[m];
  const int row0 = mlist_r[m];
  const int cnt = counts[e];
  const int col0 = colblk * BN;

  __shared__ float As[BK][LDA];  // k-major (transposed store), 16x260
  __shared__ float Bs[BK][LDB];
  __shared__ int tokS[BM];

  const int tid = threadIdx.x;
  {
    int r = row0 + tid;
    tokS[tid] = (r < cnt) ? bucket[e * N_TOK + r] : -1;
  }
  __syncthreads();

  // A-load map: rows {ar+64j, j=0..3}, k-chunk ak (4 floats) = 4 float4/thr
  const int ar = tid >> 2;
  const int ak = (tid & 3) * 4;
  // B-load map: k-row bk, col-chunk bj (8 floats = 2 float4)
  const int bk = tid >> 4;
  const int bj = (tid & 15) * 8;

  const int tx = tid & 15;  // cols tx*4 and tx*4+64
  const int ty = tid >> 4;  // row-quad base ty*4 (+64*hm)

  float acc[4][2][4][4];
#pragma unroll
  for (int hm = 0; hm < 4; ++hm)
#pragma unroll
    for (int hn = 0; hn < 2; ++hn)
#pragma unroll
      for (int i = 0; i < 4; ++i)
#pragma unroll
        for (int j = 0; j < 4; ++j) acc[hm][hn][i][j] = 0.f;

  const float* __restrict__ Ap[4];
#pragma unroll
  for (int j = 0; j < 4; ++j) {
    int tk = tokS[ar + 64 * j];
    Ap[j] = (tk >= 0) ? A + (size_t)tk * Kstride + ak : nullptr;
  }
  const float* __restrict__ Bp =
      B + (size_t)e * Kstride * Ncols + (size_t)bk * Ncols + col0 + bj;

  float4 a[4], b0, b1;

#define LOADTILE(K0)                                          \
  _Pragma("unroll") for (int j = 0; j < 4; ++j) {             \
    a[j] = make_float4(0.f, 0.f, 0.f, 0.f);                   \
    if (Ap[j]) a[j] = *(const float4*)(Ap[j] + (K0));         \
  }                                                           \
  {                                                           \
    const float* bp = Bp + (size_t)(K0) * Ncols;              \
    b0 = *(const float4*)bp;                                  \
    b1 = *(const float4*)(bp + 4);                            \
  }

  // prologue: stage tile 0 into regs
  LOADTILE(kbeg);

  const int nt = (kend - kbeg) / BK;
  for (int t = 0; t < nt; ++t) {
    __syncthreads();  // previous compute done before overwrite
#pragma unroll
    for (int j = 0; j < 4; ++j) {
      As[ak + 0][ar + 64 * j] = a[j].x;
      As[ak + 1][ar + 64 * j] = a[j].y;
      As[ak + 2][ar + 64 * j] = a[j].z;
      As[ak + 3][ar + 64 * j] = a[j].w;
    }
    *(float4*)&Bs[bk][bj] = b0;
    *(float4*)&Bs[bk][bj + 4] = b1;
    __syncthreads();

    if (t + 1 < nt) {  // prefetch next tile into regs (overlaps compute)
      const int kn = kbeg + (t + 1) * BK;
      LOADTILE(kn);
    }

#pragma unroll
    for (int kk = 0; kk < BK; ++kk) {
      float av[4][4], bv[2][4];
#pragma unroll
      for (int hm = 0; hm < 4; ++hm)
        *(float4*)&av[hm][0] = *(const float4*)&As[kk][ty * 4 + 64 * hm];
      *(float4*)&bv[0][0] = *(const float4*)&Bs[kk][tx * 4];
      *(float4*)&bv[1][0] = *(const float4*)&Bs[kk][tx * 4 + 64];
#pragma unroll
      for (int hm = 0; hm < 4; ++hm)
#pragma unroll
        for (int hn = 0; hn < 2; ++hn)
#pragma unroll
          for (int i = 0; i < 4; ++i)
#pragma unroll
            for (int j = 0; j < 4; ++j)
              acc[hm][hn][i][j] += av[hm][i] * bv[hn][j];
    }
  }
#undef LOADTILE

  if (SPLIT) {
    // raw k-slice partial, no bias/epilogue
#pragma unroll
    for (int hm = 0; hm < 4; ++hm) {
#pragma unroll
      for (int i = 0; i < 4; ++i) {
        int r = hm * 64 + ty * 4 + i;
        if (row0 + r < cnt) {
          int tok = tokS[r];
#pragma unroll
          for (int hn = 0; hn < 2; ++hn) {
            float4 o;
            o.x = acc[hm][hn][i][0];
            o.y = acc[hm][hn][i][1];
            o.z = acc[hm][hn][i][2];
            o.w = acc[hm][hn][i][3];
            *(float4*)(Cp + (size_t)tok * Ncols + col0 + hn * 64 + tx * 4) = o;
          }
        }
      }
    }
  } else {
    float4 bvv[2];
    bvv[0] = *(const float4*)(bias + (size_t)e * Ncols + col0 + tx * 4);
    bvv[1] = *(const float4*)(bias + (size_t)e * Ncols + col0 + tx * 4 + 64);
#pragma unroll
    for (int hm = 0; hm < 4; ++hm) {
#pragma unroll
      for (int i = 0; i < 4; ++i) {
        int r = hm * 64 + ty * 4 + i;
        if (row0 + r < cnt) {
          int tok = tokS[r];
#pragma unroll
          for (int hn = 0; hn < 2; ++hn) {
            const float* bb = (const float*)&bvv[hn];
            float4 o;
            o.x = fmaxf(acc[hm][hn][i][0] + bb[0], 0.f);
            o.y = fmaxf(acc[hm][hn][i][1] + bb[1], 0.f);
            o.z = fmaxf(acc[hm][hn][i][2] + bb[2], 0.f);
            o.w = fmaxf(acc[hm][hn][i][3] + bb[3], 0.f);
            *(float4*)(Cp + (size_t)tok * Ncols + col0 + hn * 64 + tx * 4) = o;
          }
        }
      }
    }
  }
}

// ---------------- split-K reduce + bias + route_p epilogue ----------------
// one block per token, 256 threads = 256 float4 covering D_MODEL=1024 cols.
__global__ __launch_bounds__(256) void moe_reduce_kernel(
    float* __restrict__ out, const float* __restrict__ partials,
    const float* __restrict__ b2, const int* __restrict__ route_idx,
    const float* __restrict__ route_p) {
  int tok = blockIdx.x;
  int c = threadIdx.x * 4;
  int e = route_idx[tok];
  float p = route_p[tok];
  size_t off = (size_t)tok * D_MODEL + c;
  float4 s = *(const float4*)(out + off);
  const size_t stride = (size_t)N_TOK * D_MODEL;
#pragma unroll
  for (int sp = 0; sp < KSPLIT - 1; ++sp) {
    float4 v = *(const float4*)(partials + sp * stride + off);
    s.x += v.x; s.y += v.y; s.z += v.z; s.w += v.w;
  }
  float4 bv = *(const float4*)(b2 + (size_t)e * D_MODEL + c);
  s.x = (s.x + bv.x) * p;
  s.y = (s.y + bv.y) * p;
  s.z = (s.z + bv.z) * p;
  s.w = (s.w + bv.w) * p;
  *(float4*)(out + off) = s;
}

extern "C" void kernel_launch(void* const* d_in, const int* in_sizes, int n_in,
                              void* d_out, int out_size, void* d_ws,
                              size_t ws_size, hipStream_t stream) {
  const float* x = (const float*)d_in[0];
  const float* w_gate = (const float*)d_in[1];
  const float* b_gate = (const float*)d_in[2];
  const float* W1 = (const float*)d_in[3];
  const float* b1 = (const float*)d_in[4];
  const float* W2 = (const float*)d_in[5];
  const float* b2 = (const float*)d_in[6];
  float* out = (float*)d_out;

  // workspace layout (~112.2 MiB)
  char* ws = (char*)d_ws;
  int* route_idx = (int*)ws;                         // 16 KiB
  float* route_p = (float*)(ws + 16384);             // 16 KiB
  int* counts = (int*)(ws + 32768);                  // 32 B
  int* Mp = (int*)(ws + 32896);                      // 4 B
  int* mlist_e = (int*)(ws + 33024);                 // <=96 B
  int* mlist_r = (int*)(ws + 33280);                 // <=96 B
  int* bucket = (int*)(ws + 33536);                  // 128 KiB
  float* H = (float*)(ws + 165888);                  // 64 MiB
  float* partials = (float*)(ws + 165888 + (size_t)67108864);  // 48 MiB

  hipMemsetAsync(counts, 0, N_EXPERTS * sizeof(int), stream);
  router_kernel<<<N_TOK, 64, 0, stream>>>(x, w_gate, b_gate, route_idx, route_p);
  bucket_kernel<<<N_TOK / 256, 256, 0, stream>>>(route_idx, counts, bucket);
  worklist_kernel<<<1, 64, 0, stream>>>(counts, mlist_e, mlist_r, Mp);
  // layer 1: H = relu(Xg @ W1 + b1); 768 compact blocks
  expert_gemm<false><<<NWG, 256, 0, stream>>>(x, W1, b1, H, nullptr, bucket,
                                              counts, mlist_e, mlist_r, Mp,
                                              D_MODEL, MLP_DIM);
  // layer 2 pass A: split-K=4 raw partials (s=0 -> out, s>0 -> ws)
  expert_gemm<true><<<NWG, 256, 0, stream>>>(H, W2, nullptr, out, partials,
                                             bucket, counts, mlist_e, mlist_r,
                                             Mp, MLP_DIM, D_MODEL);
  // layer 2 pass B: sum partials + bias + route_p scale
  moe_reduce_kernel<<<N_TOK, 256, 0, stream>>>(out, partials, b2, route_idx,
                                               route_p);
}